// Round 1
// baseline (548.867 us; speedup 1.0000x reference)
//
#include <hip/hip_runtime.h>
#include <cstdint>
#include <cstddef>

// ---------------------------------------------------------------------------
// Hyena operator, MI355X. Pipeline:
//  cast(u,W1,W2)->bf16 ; GEMM1 (bf16 MFMA, writes upT[1152][16384] bf16 +bias)
//  fftconv: per channel c (1536 blocks): DIF-FFT(k_c) -> K spectrum in regs,
//           pack (fused depthwise conv3 + pre-gate, both batches as re/im),
//           DIF-FFT, pointwise*K (bit-rev space, conj), DIT-FFT, finalize
//           (+conv_bias skip, post-gate x0) -> z[3072][8192] bf16
//  transpose z -> zt[16384][1536] ; GEMM2 (bf16 MFMA, f32 out + bias) -> d_out
// ---------------------------------------------------------------------------

using s16x8 = __attribute__((ext_vector_type(8))) short;
using f32x4 = __attribute__((ext_vector_type(4))) float;

__device__ __forceinline__ float bfu2f(unsigned short h) {
  union { unsigned int u; float f; } a; a.u = ((unsigned int)h) << 16; return a.f;
}
__device__ __forceinline__ unsigned short f2bf(float f) {
  union { float f; unsigned int u; } a; a.f = f;
  unsigned int r = a.u + 0x7fffu + ((a.u >> 16) & 1u);
  return (unsigned short)(r >> 16);
}
__device__ __forceinline__ float2 cmul(float2 a, float2 b) {
  return make_float2(a.x*b.x - a.y*b.y, a.x*b.y + a.y*b.x);
}
__device__ __forceinline__ float2 cadd(float2 a, float2 b) { return make_float2(a.x+b.x, a.y+b.y); }
__device__ __forceinline__ float2 csub(float2 a, float2 b) { return make_float2(a.x-b.x, a.y-b.y); }
__device__ __forceinline__ int SW(int p) { return p ^ ((p >> 5) & 31); }  // LDS bank swizzle

// ---------------- cast f32 -> bf16 (vectorized) ----------------
__global__ __launch_bounds__(256)
void cast_f32_to_bf16(const float* __restrict__ src, unsigned short* __restrict__ dst, const int n) {
  const int i = (blockIdx.x * 256 + threadIdx.x) * 4;
  if (i < n) {
    const float4 v = *(const float4*)(src + i);
    ushort4 o;
    o.x = f2bf(v.x); o.y = f2bf(v.y); o.z = f2bf(v.z); o.w = f2bf(v.w);
    *(ushort4*)(dst + i) = o;
  }
}

// ---------------- bf16 GEMM: C[m][n] = sum_k A[m][k]*B[n][k] + bias[n] ------
// TRANS=1: store bf16 C^T at Ct[n*M+m].  TRANS=0: store f32 C[m*N+n].
template<int TRANS>
__global__ __launch_bounds__(256)
void gemm_bt(const unsigned short* __restrict__ A, const unsigned short* __restrict__ B,
             const float* __restrict__ bias, void* __restrict__ Cout,
             const int M, const int N, const int K) {
  __shared__ unsigned short As[128 * 32];
  __shared__ unsigned short Bs[128 * 32];
  const int tid  = threadIdx.x;
  const int lane = tid & 63;
  const int wave = tid >> 6;
  const int m0 = blockIdx.x * 128;
  const int n0 = blockIdx.y * 128;
  const int wm = (wave >> 1) * 64;
  const int wn = (wave & 1) * 64;
  f32x4 acc[4][4] = {};

  const int srow = lane >> 2;        // 0..15 within 16-row group
  const int scol = (lane & 3) * 8;   // 0,8,16,24

  for (int k0 = 0; k0 < K; k0 += 32) {
    __syncthreads();
#pragma unroll
    for (int pass = 0; pass < 2; ++pass) {
      const int rbase = pass * 64 + wave * 16;
      const unsigned short* ga = A + (size_t)(m0 + rbase + srow) * K + k0 + scol;
      const unsigned short* gb = B + (size_t)(n0 + rbase + srow) * K + k0 + scol;
      __builtin_amdgcn_global_load_lds((__attribute__((address_space(1))) void*)ga,
                                       (__attribute__((address_space(3))) void*)(As + rbase * 32), 16, 0, 0);
      __builtin_amdgcn_global_load_lds((__attribute__((address_space(1))) void*)gb,
                                       (__attribute__((address_space(3))) void*)(Bs + rbase * 32), 16, 0, 0);
    }
    __syncthreads();
    s16x8 af[4], bfr[4];
#pragma unroll
    for (int i = 0; i < 4; ++i) {
      af[i]  = *(const s16x8*)(As + (wm + i * 16 + (lane & 15)) * 32 + (lane >> 4) * 8);
      bfr[i] = *(const s16x8*)(Bs + (wn + i * 16 + (lane & 15)) * 32 + (lane >> 4) * 8);
    }
#pragma unroll
    for (int mi = 0; mi < 4; ++mi)
#pragma unroll
      for (int ni = 0; ni < 4; ++ni)
        acc[mi][ni] = __builtin_amdgcn_mfma_f32_16x16x32_bf16(af[mi], bfr[ni], acc[mi][ni], 0, 0, 0);
  }
#pragma unroll
  for (int mi = 0; mi < 4; ++mi) {
#pragma unroll
    for (int ni = 0; ni < 4; ++ni) {
      const int col  = n0 + wn + ni * 16 + (lane & 15);
      const int row0 = m0 + wm + mi * 16 + (lane >> 4) * 4;
      const float bv = bias[col];
      if (TRANS) {
        unsigned short* Ct = (unsigned short*)Cout;
        ushort4 o;
        o.x = f2bf(acc[mi][ni][0] + bv);
        o.y = f2bf(acc[mi][ni][1] + bv);
        o.z = f2bf(acc[mi][ni][2] + bv);
        o.w = f2bf(acc[mi][ni][3] + bv);
        *(ushort4*)(Ct + (size_t)col * M + row0) = o;
      } else {
        float* C = (float*)Cout;
#pragma unroll
        for (int rr = 0; rr < 4; ++rr)
          C[(size_t)(row0 + rr) * N + col] = acc[mi][ni][rr] + bv;
      }
    }
  }
}

// ---------------- in-LDS FFT, N=16384 complex, 512 threads ------------------
// Radix-2 algorithm with pairs of stages fused (radix-4 butterflies), so the
// input/output permutation is the pure 14-bit bit-reversal -- which we never
// need to materialize, because forward(DIF: nat->br) and inverse(DIT: br->nat)
// cancel and the pointwise multiply is order-agnostic.
__device__ __forceinline__ void dif_fft(float2* __restrict__ buf, const int tid) {
  for (int r = 0; r < 7; ++r) {
    const int qs = 12 - 2 * r;          // q = m/4, m = 1<<(14-2r)
    const int q  = 1 << qs;
    const float angf = -6.2831853071795864769f / (float)(1 << (14 - 2 * r));
#pragma unroll
    for (int it = 0; it < 8; ++it) {
      const int id = tid + it * 512;
      const int j  = id & (q - 1);
      const int p0 = ((id >> qs) << (qs + 2)) + j;
      float2 x0 = buf[SW(p0)];
      float2 x1 = buf[SW(p0 + q)];
      float2 x2 = buf[SW(p0 + 2 * q)];
      float2 x3 = buf[SW(p0 + 3 * q)];
      float sn, cs;
      __sincosf(angf * (float)j, &sn, &cs);
      const float2 w1 = make_float2(cs, sn);
      const float2 w2 = cmul(w1, w1);
      const float2 ta = cadd(x0, x2), tb = csub(x0, x2);
      const float2 ua = cadd(x1, x3), ub = csub(x1, x3);
      const float2 v02 = cmul(tb, w1);
      float2 v13 = cmul(ub, w1);
      v13 = make_float2(v13.y, -v13.x);            // * (-i)
      buf[SW(p0)]         = cadd(ta, ua);
      buf[SW(p0 + q)]     = cmul(csub(ta, ua), w2);
      buf[SW(p0 + 2 * q)] = cadd(v02, v13);
      buf[SW(p0 + 3 * q)] = cmul(csub(v02, v13), w2);
    }
    __syncthreads();
  }
}

__device__ __forceinline__ void dit_fft(float2* __restrict__ buf, const int tid) {
  for (int r = 0; r < 7; ++r) {
    const int qs = 2 * r;               // q = m/2, m = 1<<(2r+1)
    const int q  = 1 << qs;
    const float angf = -6.2831853071795864769f / (float)(1 << (2 * r + 2));
#pragma unroll
    for (int it = 0; it < 8; ++it) {
      const int id = tid + it * 512;
      const int j  = id & (q - 1);
      const int p0 = ((id >> qs) << (qs + 2)) + j;
      float2 x0 = buf[SW(p0)];
      float2 x1 = buf[SW(p0 + q)];
      float2 x2 = buf[SW(p0 + 2 * q)];
      float2 x3 = buf[SW(p0 + 3 * q)];
      float sn, cs;
      __sincosf(angf * (float)j, &sn, &cs);
      const float2 w1 = make_float2(cs, sn);
      const float2 w2 = cmul(w1, w1);
      const float2 t1 = cmul(x1, w2);
      const float2 y0 = cadd(x0, t1), y1 = csub(x0, t1);
      const float2 t3 = cmul(x3, w2);
      const float2 y2 = cadd(x2, t3), y3 = csub(x2, t3);
      const float2 t  = cmul(y2, w1);
      float2 t4 = cmul(y3, w1);
      t4 = make_float2(t4.y, -t4.x);               // * (-i)
      buf[SW(p0)]         = cadd(y0, t);
      buf[SW(p0 + q)]     = cadd(y1, t4);
      buf[SW(p0 + 2 * q)] = csub(y0, t);
      buf[SW(p0 + 3 * q)] = csub(y1, t4);
    }
    __syncthreads();
  }
}

// ---------------- fused shortconv + gate + FFT long conv --------------------
__global__ __launch_bounds__(512)
void hyena_fftconv(const unsigned short* __restrict__ upT,  // [1152][16384] bf16
                   const float* __restrict__ kmat,          // [1536][8192]
                   const float* __restrict__ short_w,       // [4608][3]
                   const float* __restrict__ short_b,       // [4608]
                   const float* __restrict__ conv_bias,     // [1536]
                   unsigned short* __restrict__ z) {        // [3072][8192] bf16
  __shared__ float2 buf[16384];                              // 128 KB
  const int tid = threadIdx.x;
  const int c   = blockIdx.x;                                // channel 0..1535

  // ---- K spectrum (zero-padded real kernel, full complex DFT, br order) ----
  const float* kr = kmat + (size_t)c * 8192;
#pragma unroll
  for (int i = 0; i < 32; ++i) {
    const int n = tid + i * 512;
    float2 v = make_float2(0.f, 0.f);
    if (n < 8192) v.x = kr[n];
    buf[SW(n)] = v;
  }
  __syncthreads();
  dif_fft(buf, tid);
  float2 kf[32];
#pragma unroll
  for (int i = 0; i < 32; ++i) kf[i] = buf[SW(tid + i * 512)];
  __syncthreads();

  // ---- pack: fused depthwise conv3 + pre-gate; batch0 = re, batch1 = im ----
  const int c0 = c % 1152;
  const int c1 = (c + 384) % 1152;
  const int c2 = (c + 768) % 1152;
  const unsigned short* r0 = upT + (size_t)c0 * 16384;
  const unsigned short* r1 = upT + (size_t)c1 * 16384;
  const unsigned short* r2 = upT + (size_t)c2 * 16384;
  float w0[3], w1v[3], w2v[3];
#pragma unroll
  for (int j = 0; j < 3; ++j) {
    w0[j]  = short_w[(size_t)c * 3 + j];
    w1v[j] = short_w[(size_t)(1536 + c) * 3 + j];
    w2v[j] = short_w[(size_t)(3072 + c) * 3 + j];
  }
  const float b0 = short_b[c], b1s = short_b[1536 + c], b2s = short_b[3072 + c];
  float x0a[16], x0b[16], vpa[16], vpb[16];
#pragma unroll
  for (int i = 0; i < 16; ++i) {
    const int n = tid + i * 512;
    float s0a = b0, s1a = b1s, s2a = b2s;
    float s0b = b0, s1b = b1s, s2b = b2s;
#pragma unroll
    for (int j = 0; j < 3; ++j) {
      const int t = n - 2 + j;
      if (t >= 0) {
        s0a += w0[j]  * bfu2f(r0[t]);
        s1a += w1v[j] * bfu2f(r1[t]);
        s2a += w2v[j] * bfu2f(r2[t]);
        s0b += w0[j]  * bfu2f(r0[8192 + t]);
        s1b += w1v[j] * bfu2f(r1[8192 + t]);
        s2b += w2v[j] * bfu2f(r2[8192 + t]);
      }
    }
    x0a[i] = s0a; x0b[i] = s0b;
    vpa[i] = s2a * s1a; vpb[i] = s2b * s1b;
    buf[SW(n)] = make_float2(vpa[i], vpb[i]);
  }
#pragma unroll
  for (int i = 16; i < 32; ++i) buf[SW(tid + i * 512)] = make_float2(0.f, 0.f);
  __syncthreads();
  dif_fft(buf, tid);

  // ---- pointwise multiply by K, store conj for inverse-via-forward-DIT ----
#pragma unroll
  for (int i = 0; i < 32; ++i) {
    const int p = SW(tid + i * 512);
    const float2 a = buf[p], b = kf[i];
    buf[p] = make_float2(a.x * b.x - a.y * b.y, -(a.x * b.y + a.y * b.x));
  }
  __syncthreads();
  dit_fft(buf, tid);

  // ---- finalize: y = conj(F)/N ; add conv_bias skip ; post-gate by x0 ----
  const float cb  = conv_bias[c];
  const float inv = 1.0f / 16384.0f;
  unsigned short* za = z + (size_t)c * 8192;
  unsigned short* zb = z + (size_t)(1536 + c) * 8192;
#pragma unroll
  for (int i = 0; i < 16; ++i) {
    const int n = tid + i * 512;
    const float2 F = buf[SW(n)];
    const float ya =  F.x * inv;
    const float yb = -F.y * inv;
    za[n] = f2bf((ya + vpa[i] * cb) * x0a[i]);
    zb[n] = f2bf((yb + vpb[i] * cb) * x0b[i]);
  }
}

// ---------------- transpose z[3072][8192] -> zt[16384][1536] ----------------
__global__ __launch_bounds__(256)
void transpose_z(const unsigned short* __restrict__ z, unsigned short* __restrict__ zt) {
  __shared__ unsigned short tile[64][65];
  const int tid = threadIdx.x;
  const int ct = blockIdx.x;   // 0..23  (c tiles)
  const int tt = blockIdx.y;   // 0..127 (t tiles)
  const int b  = blockIdx.z;   // 0..1
#pragma unroll
  for (int p = 0; p < 2; ++p) {
    const int idx = p * 256 + tid;
    const int row = idx >> 3;  // local c
    const int c8  = idx & 7;
    const uint4 v = *(const uint4*)(z + (size_t)(b * 1536 + ct * 64 + row) * 8192 + tt * 64 + c8 * 8);
    unsigned short* tp = &tile[row][c8 * 8];
    tp[0] = (unsigned short)(v.x & 0xffff); tp[1] = (unsigned short)(v.x >> 16);
    tp[2] = (unsigned short)(v.y & 0xffff); tp[3] = (unsigned short)(v.y >> 16);
    tp[4] = (unsigned short)(v.z & 0xffff); tp[5] = (unsigned short)(v.z >> 16);
    tp[6] = (unsigned short)(v.w & 0xffff); tp[7] = (unsigned short)(v.w >> 16);
  }
  __syncthreads();
#pragma unroll
  for (int p = 0; p < 2; ++p) {
    const int idx  = p * 256 + tid;
    const int trow = idx >> 3;  // local t
    const int cc   = idx & 7;
    uint4 o;
    o.x = (unsigned)tile[cc * 8 + 0][trow] | ((unsigned)tile[cc * 8 + 1][trow] << 16);
    o.y = (unsigned)tile[cc * 8 + 2][trow] | ((unsigned)tile[cc * 8 + 3][trow] << 16);
    o.z = (unsigned)tile[cc * 8 + 4][trow] | ((unsigned)tile[cc * 8 + 5][trow] << 16);
    o.w = (unsigned)tile[cc * 8 + 6][trow] | ((unsigned)tile[cc * 8 + 7][trow] << 16);
    *(uint4*)(zt + (size_t)(b * 8192 + tt * 64 + trow) * 1536 + ct * 64 + cc * 8) = o;
  }
}

// ---------------------------------------------------------------------------
extern "C" void kernel_launch(void* const* d_in, const int* in_sizes, int n_in,
                              void* d_out, int out_size, void* d_ws, size_t ws_size,
                              hipStream_t stream) {
  const float* u   = (const float*)d_in[0];   // [2,8192,768]
  const float* w1  = (const float*)d_in[1];   // [1152,768]
  const float* b1  = (const float*)d_in[2];   // [1152]
  const float* sw  = (const float*)d_in[3];   // [4608,1,3]
  const float* sb  = (const float*)d_in[4];   // [4608]
  const float* km  = (const float*)d_in[5];   // [1536,8192]
  const float* cb  = (const float*)d_in[6];   // [1536]
  const float* w2  = (const float*)d_in[7];   // [768,1536]
  const float* b2  = (const float*)d_in[8];   // [768]
  float* outp = (float*)d_out;                // [2,8192,768]

  char* ws = (char*)d_ws;
  unsigned short* u_bf  = (unsigned short*)(ws);               // 25165824 B
  unsigned short* w1_bf = (unsigned short*)(ws + 25165824);    //  1769472 B
  unsigned short* w2_bf = (unsigned short*)(ws + 26935296);    //  2359296 B
  unsigned short* upT   = (unsigned short*)(ws + 29294592);    // 37748736 B
  unsigned short* zbuf  = (unsigned short*)(ws + 67043328);    // 50331648 B
  unsigned short* ztb   = (unsigned short*)(ws + 117374976);   // 50331648 B

  cast_f32_to_bf16<<<12288, 256, 0, stream>>>(u,  u_bf,  12582912);
  cast_f32_to_bf16<<<  864, 256, 0, stream>>>(w1, w1_bf,   884736);
  cast_f32_to_bf16<<< 1152, 256, 0, stream>>>(w2, w2_bf,  1179648);

  dim3 g1(128, 9);
  gemm_bt<1><<<g1, 256, 0, stream>>>(u_bf, w1_bf, b1, upT, 16384, 1152, 768);

  hyena_fftconv<<<1536, 512, 0, stream>>>(upT, km, sw, sb, cb, zbuf);

  transpose_z<<<dim3(24, 128, 2), 256, 0, stream>>>(zbuf, ztb);

  dim3 g2(128, 6);
  gemm_bt<0><<<g2, 256, 0, stream>>>(ztb, w2_bf, b2, outp, 16384, 768, 1536);
}